// Round 11
// baseline (341.282 us; speedup 1.0000x reference)
//
#include <hip/hip_runtime.h>
#include <hip/hip_fp16.h>

typedef __attribute__((ext_vector_type(8))) short f16x8;
typedef __attribute__((ext_vector_type(8))) _Float16 half8;
typedef __attribute__((ext_vector_type(16))) float f32x16;

__device__ __forceinline__ unsigned short f2h(float x) {
    __half h = __float2half(x);           // RNE f32 -> f16
    unsigned short u;
    __builtin_memcpy(&u, &h, 2);
    return u;
}

// async global->LDS, 16B per lane. LDS dest = wave-uniform base + lane*16.
__device__ __forceinline__ void gll16(const void* g, void* l) {
    __builtin_amdgcn_global_load_lds(
        (const __attribute__((address_space(1))) unsigned*)g,
        (__attribute__((address_space(3))) unsigned*)l, 16, 0, 0);
}

// ---------------- kernel 1: L2-normalize rows, f32 -> f16 (196-row panels) ----
__global__ __launch_bounds__(256) void norm_kernel(
    const float* __restrict__ feats, const float* __restrict__ nfeats,
    unsigned short* __restrict__ fH, unsigned short* __restrict__ nfH,
    unsigned* __restrict__ smaxG)
{
    int idx = blockIdx.x * 256 + threadIdx.x;
    if (idx < 32 * 64 * 208) smaxG[idx] = 0u;          // zero accumulators (replay-safe)

    int row  = blockIdx.x * 4 + (threadIdx.x >> 6);    // one wave per row, rows 0..18815
    int lane = threadIdx.x & 63;
    const float* src;
    unsigned short* dst;
    if (row < 6272) { src = feats  + (size_t)row * 128; dst = fH  + (size_t)row * 128; }
    else { int r2 = row - 6272; src = nfeats + (size_t)r2 * 128; dst = nfH + (size_t)r2 * 128; }

    float2 v = *(const float2*)(src + lane * 2);
    float ss = v.x * v.x + v.y * v.y;
    #pragma unroll
    for (int m = 1; m < 64; m <<= 1) ss += __shfl_xor(ss, m, 64);
    float rn = rsqrtf(ss);
    ushort2 o; o.x = f2h(v.x * rn); o.y = f2h(v.y * rn);
    *(ushort2*)(dst + lane * 2) = o;
}

// ---------------- kernel 2: swapped-operand MFMA, reg-held fold, 1 barrier/bi ----
// Stage a 196x128 f16 panel (3136 16B chunks), source-side swizzled:
// LDS slot (row, cc) holds global chunk (row, cc ^ (row&7)).  1024 threads.
__device__ __forceinline__ void stage196(const f16x8* __restrict__ g, f16x8* l,
                                         int tid, int wave) {
    #pragma unroll
    for (int i = 0; i < 3; ++i) {
        int slot = i * 1024 + tid;
        int row = slot >> 4, cc = slot & 15;
        gll16(g + row * 16 + (cc ^ (row & 7)), l + i * 1024 + wave * 64);
    }
    if (tid < 64) {                        // tail: slots 3072..3135 (rows 192..195)
        int slot = 3072 + tid;
        int row = slot >> 4, cc = slot & 15;
        gll16(g + row * 16 + (cc ^ (row & 7)), l + 3072);
    }
}

// Uniform 2x2 32-tile cell: q-pair (A-operand = nf) x p-pair (B-operand = f), K=128.
// C/D: col = lane&31 = p, row = q. Fold max over q in-register -> rm[2] (pre-shfl).
__device__ __forceinline__ void cells22(
    const f16x8* __restrict__ Np, const f16x8* __restrict__ Fp,
    int q0, int p0, int l31, int h, float (&rm)[2])
{
    f32x16 acc[2][2];
    #pragma unroll
    for (int m = 0; m < 2; ++m)
        #pragma unroll
        for (int n = 0; n < 2; ++n)
            #pragma unroll
            for (int r = 0; r < 16; ++r) acc[m][n][r] = 0.0f;

    #pragma unroll
    for (int kk = 0; kk < 8; ++kk) {
        half8 qa[2], pb[2];
        #pragma unroll
        for (int m = 0; m < 2; ++m) {
            int row = q0 + m * 32 + l31;
            qa[m] = *(const half8*)(Np + ((row << 4) | ((kk * 2 + h) ^ (row & 7))));
        }
        #pragma unroll
        for (int n = 0; n < 2; ++n) {
            int row = p0 + n * 32 + l31;
            pb[n] = *(const half8*)(Fp + ((row << 4) | ((kk * 2 + h) ^ (row & 7))));
        }
        #pragma unroll
        for (int m = 0; m < 2; ++m)
            #pragma unroll
            for (int n = 0; n < 2; ++n)
                acc[m][n] = __builtin_amdgcn_mfma_f32_32x32x16_f16(qa[m], pb[n], acc[m][n], 0, 0, 0);
    }

    #pragma unroll
    for (int n = 0; n < 2; ++n) {
        float c0 = -3.0f, c1 = -3.0f, c2 = -3.0f, c3 = -3.0f;
        #pragma unroll
        for (int m = 0; m < 2; ++m)
            #pragma unroll
            for (int r = 0; r < 16; ++r) {
                float x = acc[m][n][r];
                if ((r & 3) == 0) c0 = fmaxf(c0, x);
                else if ((r & 3) == 1) c1 = fmaxf(c1, x);
                else if ((r & 3) == 2) c2 = fmaxf(c2, x);
                else c3 = fmaxf(c3, x);
            }
        rm[n] = fmaxf(fmaxf(c0, c1), fmaxf(c2, c3));
    }
}

__global__ __launch_bounds__(1024) void simmax_kernel(
    const unsigned short* __restrict__ fH, const unsigned short* __restrict__ nfH,
    unsigned* __restrict__ smaxG)
{
    __shared__ f16x8 lds[3 * 3136];       // F | B0 | B1 = 150,528 B
    f16x8* Fl = lds;
    f16x8* B0 = lds + 3136;
    f16x8* B1 = lds + 6272;

    int a = blockIdx.x & 31, bg = blockIdx.x >> 5;   // 256 blocks = 1/CU
    int b0 = bg * 8;
    int tid = threadIdx.x, wave = tid >> 6, lane = tid & 63;
    int l31 = lane & 31, h = lane >> 5;
    int qg = wave & 3, pg = wave >> 2;               // uniform 2x2 cells; tile 6 @132
    int q0 = (qg < 3) ? qg * 64 : 132;               // rows always < 196: no masking
    int p0 = (pg < 3) ? pg * 64 : 132;

    stage196((const f16x8*)(fH  + (size_t)a  * 196 * 128), Fl, tid, wave);
    stage196((const f16x8*)(nfH + (size_t)b0 * 196 * 128), B0, tid, wave);
    __syncthreads();

    float rmA[8], rmB[8];                 // statically indexed (bi loop unrolled)
    #pragma unroll
    for (int bi = 0; bi < 8; ++bi) {
        f16x8* Bcur = (bi & 1) ? B1 : B0;
        f16x8* Bnxt = (bi & 1) ? B0 : B1;
        if (bi < 7)                       // async; lands during this bi's compute
            stage196((const f16x8*)(nfH + (size_t)(b0 + bi + 1) * 196 * 128), Bnxt, tid, wave);
        float rm[2];
        cells22(Bcur, Fl, q0, p0, l31, h, rm);
        rmA[bi] = rm[0]; rmB[bi] = rm[1];
        __syncthreads();                  // Bcur free for re-stage; Bnxt drained
    }

    // tail: combine row-halves, one global atomicMax per (bi, p) partial
    unsigned* sG = smaxG + ((size_t)a * 64 + b0) * 208;
    #pragma unroll
    for (int bi = 0; bi < 8; ++bi) {
        float v0 = rmA[bi]; v0 = fmaxf(v0, __shfl_xor(v0, 32, 64));
        float v1 = rmB[bi]; v1 = fmaxf(v1, __shfl_xor(v1, 32, 64));
        if (h == 0) {
            atomicMax(&sG[bi * 208 + p0 + l31],      __float_as_uint(v0 + 3.0f));
            atomicMax(&sG[bi * 208 + p0 + 32 + l31], __float_as_uint(v1 + 3.0f));
        }
    }
}

// ---------------- kernel 3: smaxG -> dist, scores[a][b] max, patch mean, out[a] ----
__global__ __launch_bounds__(256) void finalize_kernel(
    const unsigned* __restrict__ smaxG, const float* __restrict__ mask,
    float* __restrict__ patch, float* __restrict__ out)
{
    int a = blockIdx.x, tid = threadIdx.x, wave = tid >> 6, lane = tid & 63;
    __shared__ float psumL[4][208];
    __shared__ float scb[64];

    float mk[4], ps[4] = {0.f, 0.f, 0.f, 0.f};
    #pragma unroll
    for (int j = 0; j < 4; ++j) {
        int p = lane + 64 * j;
        mk[j] = (p < 196) ? mask[a * 196 + p] : 0.0f;
    }
    const unsigned* base = smaxG + (size_t)a * 64 * 208;
    for (int k = 0; k < 16; ++k) {        // each wave: 16 b's
        int b = wave * 16 + k;
        float bmax = 0.0f;
        #pragma unroll
        for (int j = 0; j < 4; ++j) {
            int p = lane + 64 * j;
            float d = 0.0f;
            if (p < 196) {
                float sim = __uint_as_float(base[b * 208 + p]) - 3.0f;
                d = 0.5f * sqrtf(fmaxf(2.0f - 2.0f * sim, 0.0f)) * mk[j];
            }
            ps[j] += d;
            bmax = fmaxf(bmax, d);
        }
        #pragma unroll
        for (int m = 1; m < 64; m <<= 1) bmax = fmaxf(bmax, __shfl_xor(bmax, m, 64));
        if (lane == 0) scb[b] = bmax;
    }
    #pragma unroll
    for (int j = 0; j < 4; ++j) {
        int p = lane + 64 * j;
        if (p < 208) psumL[wave][p] = ps[j];
    }
    __syncthreads();
    if (tid < 196) {
        float s = psumL[0][tid] + psumL[1][tid] + psumL[2][tid] + psumL[3][tid];
        patch[a * 196 + tid] = s * (1.0f / 64.0f);
    }
    if (wave == 0) {                      // mean of per-b maxima -> out[a]
        float s = scb[lane];
        #pragma unroll
        for (int m = 1; m < 64; m <<= 1) s += __shfl_xor(s, m, 64);
        if (lane == 0) out[a] = s * (1.0f / 64.0f);
    }
}

// ---------------- kernel 4: bilinear 14x14 -> 224x224, 8-row bands ----
__global__ __launch_bounds__(256) void upsample_kernel(
    const float* __restrict__ patch, float* __restrict__ out)
{
    int bid = blockIdx.x;
    int a = bid / 28, band = bid % 28;
    __shared__ float pt[196];
    if (threadIdx.x < 196) pt[threadIdx.x] = patch[a * 196 + threadIdx.x];
    __syncthreads();

    float* op = out + 32 + (size_t)a * 50176 + band * 8 * 224;
    for (int t = threadIdx.x; t < 8 * 224; t += 256) {
        int h = band * 8 + (t / 224), w = t % 224;
        float sh = fmaxf((h + 0.5f) * 0.0625f - 0.5f, 0.0f);   // 14/224 = 1/16
        float sw = fmaxf((w + 0.5f) * 0.0625f - 0.5f, 0.0f);
        int h0 = (int)sh, w0 = (int)sw;
        int h1 = min(h0 + 1, 13), w1 = min(w0 + 1, 13);
        float fh = sh - (float)h0, fw = sw - (float)w0;
        float v00 = pt[h0 * 14 + w0], v01 = pt[h0 * 14 + w1];
        float v10 = pt[h1 * 14 + w0], v11 = pt[h1 * 14 + w1];
        op[t] = (1.0f - fh) * ((1.0f - fw) * v00 + fw * v01)
              +         fh  * ((1.0f - fw) * v10 + fw * v11);
    }
}

extern "C" void kernel_launch(void* const* d_in, const int* in_sizes, int n_in,
                              void* d_out, int out_size, void* d_ws, size_t ws_size,
                              hipStream_t stream) {
    const float* feats  = (const float*)d_in[0];   // [32,196,128]
    const float* nfeats = (const float*)d_in[1];   // [64,196,128]
    const float* mask   = (const float*)d_in[2];   // [32,196]
    float* out = (float*)d_out;                    // 32 + 32*224*224

    char* w = (char*)d_ws;
    unsigned short* fH  = (unsigned short*)(w);            // 32*196*128 f16 = 1,605,632 B
    unsigned short* nfH = (unsigned short*)(w + 1605632);  // 64*196*128 f16 = 3,211,264 B
    unsigned* smaxG     = (unsigned*)(w + 4816896);        // 32*64*208 u32  = 1,703,936 B
    float* patch        = (float*)(w + 6520832);           // 32*196 f32

    norm_kernel<<<4704, 256, 0, stream>>>(feats, nfeats, fH, nfH, smaxG);
    simmax_kernel<<<256, 1024, 0, stream>>>(fH, nfH, smaxG);
    finalize_kernel<<<32, 256, 0, stream>>>(smaxG, mask, patch, out);
    upsample_kernel<<<896, 256, 0, stream>>>(patch, out);
}

// Round 12
// 62.403 us; speedup vs baseline: 5.4690x; 5.4690x over previous
//
#include <hip/hip_runtime.h>
#include <hip/hip_fp16.h>

typedef __attribute__((ext_vector_type(8))) short f16x8;
typedef __attribute__((ext_vector_type(8))) _Float16 half8;
typedef __attribute__((ext_vector_type(16))) float f32x16;

__device__ __forceinline__ unsigned short f2h(float x) {
    __half h = __float2half(x);           // RNE f32 -> f16
    unsigned short u;
    __builtin_memcpy(&u, &h, 2);
    return u;
}

// async global->LDS, 16B per lane. LDS dest = wave-uniform base + lane*16.
__device__ __forceinline__ void gll16(const void* g, void* l) {
    __builtin_amdgcn_global_load_lds(
        (const __attribute__((address_space(1))) unsigned*)g,
        (__attribute__((address_space(3))) unsigned*)l, 16, 0, 0);
}

// ---------------- kernel 1: L2-normalize rows, f32 -> f16 (196-row panels) ----
__global__ __launch_bounds__(256) void norm_kernel(
    const float* __restrict__ feats, const float* __restrict__ nfeats,
    unsigned short* __restrict__ fH, unsigned short* __restrict__ nfH,
    unsigned* __restrict__ smaxG)
{
    int idx = blockIdx.x * 256 + threadIdx.x;
    if (idx < 32 * 64 * 208) smaxG[idx] = 0u;          // zero accumulators (replay-safe)

    int row  = blockIdx.x * 4 + (threadIdx.x >> 6);    // one wave per row, rows 0..18815
    int lane = threadIdx.x & 63;
    const float* src;
    unsigned short* dst;
    if (row < 6272) { src = feats  + (size_t)row * 128; dst = fH  + (size_t)row * 128; }
    else { int r2 = row - 6272; src = nfeats + (size_t)r2 * 128; dst = nfH + (size_t)r2 * 128; }

    float2 v = *(const float2*)(src + lane * 2);
    float ss = v.x * v.x + v.y * v.y;
    #pragma unroll
    for (int m = 1; m < 64; m <<= 1) ss += __shfl_xor(ss, m, 64);
    float rn = rsqrtf(ss);
    ushort2 o; o.x = f2h(v.x * rn); o.y = f2h(v.y * rn);
    *(ushort2*)(dst + lane * 2) = o;
}

// ---------------- kernel 2: swapped-operand MFMA, per-bi fold + global atomic ----
// Stage a 196x128 f16 panel (3136 16B chunks), source-side swizzled:
// LDS slot (row, cc) holds global chunk (row, cc ^ (row&7)).  1024 threads.
__device__ __forceinline__ void stage196(const f16x8* __restrict__ g, f16x8* l,
                                         int tid, int wave) {
    #pragma unroll
    for (int i = 0; i < 3; ++i) {
        int slot = i * 1024 + tid;
        int row = slot >> 4, cc = slot & 15;
        gll16(g + row * 16 + (cc ^ (row & 7)), l + i * 1024 + wave * 64);
    }
    if (tid < 64) {                        // tail: slots 3072..3135 (rows 192..195)
        int slot = 3072 + tid;
        int row = slot >> 4, cc = slot & 15;
        gll16(g + row * 16 + (cc ^ (row & 7)), l + 3072);
    }
}

// Uniform 2x2 32-tile cell: q-pair (A-operand = nf) x p-pair (B-operand = f), K=128.
// C/D: col = lane&31 = p, row = q. Fold max over q in-register; consume
// immediately: shfl row-halves + global atomicMax (no state kept across bi).
__device__ __forceinline__ void cells22(
    const f16x8* __restrict__ Np, const f16x8* __restrict__ Fp,
    int q0, int p0, int l31, int h, unsigned* __restrict__ sGbi)
{
    f32x16 acc[2][2];
    #pragma unroll
    for (int m = 0; m < 2; ++m)
        #pragma unroll
        for (int n = 0; n < 2; ++n)
            #pragma unroll
            for (int r = 0; r < 16; ++r) acc[m][n][r] = 0.0f;

    #pragma unroll
    for (int kk = 0; kk < 8; ++kk) {
        half8 qa[2], pb[2];
        #pragma unroll
        for (int m = 0; m < 2; ++m) {
            int row = q0 + m * 32 + l31;
            qa[m] = *(const half8*)(Np + ((row << 4) | ((kk * 2 + h) ^ (row & 7))));
        }
        #pragma unroll
        for (int n = 0; n < 2; ++n) {
            int row = p0 + n * 32 + l31;
            pb[n] = *(const half8*)(Fp + ((row << 4) | ((kk * 2 + h) ^ (row & 7))));
        }
        #pragma unroll
        for (int m = 0; m < 2; ++m)
            #pragma unroll
            for (int n = 0; n < 2; ++n)
                acc[m][n] = __builtin_amdgcn_mfma_f32_32x32x16_f16(qa[m], pb[n], acc[m][n], 0, 0, 0);
    }

    #pragma unroll
    for (int n = 0; n < 2; ++n) {
        float c0 = -3.0f, c1 = -3.0f, c2 = -3.0f, c3 = -3.0f;
        #pragma unroll
        for (int m = 0; m < 2; ++m)
            #pragma unroll
            for (int r = 0; r < 16; ++r) {
                float x = acc[m][n][r];
                if ((r & 3) == 0) c0 = fmaxf(c0, x);
                else if ((r & 3) == 1) c1 = fmaxf(c1, x);
                else if ((r & 3) == 2) c2 = fmaxf(c2, x);
                else c3 = fmaxf(c3, x);
            }
        float v = fmaxf(fmaxf(c0, c1), fmaxf(c2, c3));
        v = fmaxf(v, __shfl_xor(v, 32, 64));            // combine row-halves (h)
        if (h == 0)                                      // lanes 0-31: one per p
            atomicMax(&sGbi[p0 + n * 32 + l31], __float_as_uint(v + 3.0f));
    }
}

__global__ __launch_bounds__(1024, 4) void simmax_kernel(
    const unsigned short* __restrict__ fH, const unsigned short* __restrict__ nfH,
    unsigned* __restrict__ smaxG)
{
    __shared__ f16x8 lds[3 * 3136];       // F | B0 | B1 = 150,528 B
    f16x8* Fl = lds;
    f16x8* B0 = lds + 3136;
    f16x8* B1 = lds + 6272;

    int a = blockIdx.x & 31, bg = blockIdx.x >> 5;   // 256 blocks = 1/CU
    int b0 = bg * 8;
    int tid = threadIdx.x, wave = tid >> 6, lane = tid & 63;
    int l31 = lane & 31, h = lane >> 5;
    int qg = wave & 3, pg = wave >> 2;               // uniform 2x2 cells; tile 6 @132
    int q0 = (qg < 3) ? qg * 64 : 132;               // rows always < 196: no masking
    int p0 = (pg < 3) ? pg * 64 : 132;

    stage196((const f16x8*)(fH  + (size_t)a  * 196 * 128), Fl, tid, wave);
    stage196((const f16x8*)(nfH + (size_t)b0 * 196 * 128), B0, tid, wave);
    __syncthreads();

    unsigned* sG = smaxG + ((size_t)a * 64 + b0) * 208;
    #pragma unroll
    for (int bi = 0; bi < 8; ++bi) {
        f16x8* Bcur = (bi & 1) ? B1 : B0;
        f16x8* Bnxt = (bi & 1) ? B0 : B1;
        if (bi < 7)                       // async; lands during this bi's compute
            stage196((const f16x8*)(nfH + (size_t)(b0 + bi + 1) * 196 * 128), Bnxt, tid, wave);
        cells22(Bcur, Fl, q0, p0, l31, h, sG + bi * 208);
        __syncthreads();                  // Bcur free for re-stage; Bnxt drained
    }
}

// ---------------- kernel 3: smaxG -> dist, scores[a][b] max, patch mean, out[a] ----
__global__ __launch_bounds__(256) void finalize_kernel(
    const unsigned* __restrict__ smaxG, const float* __restrict__ mask,
    float* __restrict__ patch, float* __restrict__ out)
{
    int a = blockIdx.x, tid = threadIdx.x, wave = tid >> 6, lane = tid & 63;
    __shared__ float psumL[4][208];
    __shared__ float scb[64];

    float mk[4], ps[4] = {0.f, 0.f, 0.f, 0.f};
    #pragma unroll
    for (int j = 0; j < 4; ++j) {
        int p = lane + 64 * j;
        mk[j] = (p < 196) ? mask[a * 196 + p] : 0.0f;
    }
    const unsigned* base = smaxG + (size_t)a * 64 * 208;
    for (int k = 0; k < 16; ++k) {        // each wave: 16 b's
        int b = wave * 16 + k;
        float bmax = 0.0f;
        #pragma unroll
        for (int j = 0; j < 4; ++j) {
            int p = lane + 64 * j;
            float d = 0.0f;
            if (p < 196) {
                float sim = __uint_as_float(base[b * 208 + p]) - 3.0f;
                d = 0.5f * sqrtf(fmaxf(2.0f - 2.0f * sim, 0.0f)) * mk[j];
            }
            ps[j] += d;
            bmax = fmaxf(bmax, d);
        }
        #pragma unroll
        for (int m = 1; m < 64; m <<= 1) bmax = fmaxf(bmax, __shfl_xor(bmax, m, 64));
        if (lane == 0) scb[b] = bmax;
    }
    #pragma unroll
    for (int j = 0; j < 4; ++j) {
        int p = lane + 64 * j;
        if (p < 208) psumL[wave][p] = ps[j];
    }
    __syncthreads();
    if (tid < 196) {
        float s = psumL[0][tid] + psumL[1][tid] + psumL[2][tid] + psumL[3][tid];
        patch[a * 196 + tid] = s * (1.0f / 64.0f);
    }
    if (wave == 0) {                      // mean of per-b maxima -> out[a]
        float s = scb[lane];
        #pragma unroll
        for (int m = 1; m < 64; m <<= 1) s += __shfl_xor(s, m, 64);
        if (lane == 0) out[a] = s * (1.0f / 64.0f);
    }
}

// ---------------- kernel 4: bilinear 14x14 -> 224x224, 8-row bands ----
__global__ __launch_bounds__(256) void upsample_kernel(
    const float* __restrict__ patch, float* __restrict__ out)
{
    int bid = blockIdx.x;
    int a = bid / 28, band = bid % 28;
    __shared__ float pt[196];
    if (threadIdx.x < 196) pt[threadIdx.x] = patch[a * 196 + threadIdx.x];
    __syncthreads();

    float* op = out + 32 + (size_t)a * 50176 + band * 8 * 224;
    for (int t = threadIdx.x; t < 8 * 224; t += 256) {
        int h = band * 8 + (t / 224), w = t % 224;
        float sh = fmaxf((h + 0.5f) * 0.0625f - 0.5f, 0.0f);   // 14/224 = 1/16
        float sw = fmaxf((w + 0.5f) * 0.0625f - 0.5f, 0.0f);
        int h0 = (int)sh, w0 = (int)sw;
        int h1 = min(h0 + 1, 13), w1 = min(w0 + 1, 13);
        float fh = sh - (float)h0, fw = sw - (float)w0;
        float v00 = pt[h0 * 14 + w0], v01 = pt[h0 * 14 + w1];
        float v10 = pt[h1 * 14 + w0], v11 = pt[h1 * 14 + w1];
        op[t] = (1.0f - fh) * ((1.0f - fw) * v00 + fw * v01)
              +         fh  * ((1.0f - fw) * v10 + fw * v11);
    }
}

extern "C" void kernel_launch(void* const* d_in, const int* in_sizes, int n_in,
                              void* d_out, int out_size, void* d_ws, size_t ws_size,
                              hipStream_t stream) {
    const float* feats  = (const float*)d_in[0];   // [32,196,128]
    const float* nfeats = (const float*)d_in[1];   // [64,196,128]
    const float* mask   = (const float*)d_in[2];   // [32,196]
    float* out = (float*)d_out;                    // 32 + 32*224*224

    char* w = (char*)d_ws;
    unsigned short* fH  = (unsigned short*)(w);            // 32*196*128 f16 = 1,605,632 B
    unsigned short* nfH = (unsigned short*)(w + 1605632);  // 64*196*128 f16 = 3,211,264 B
    unsigned* smaxG     = (unsigned*)(w + 4816896);        // 32*64*208 u32  = 1,703,936 B
    float* patch        = (float*)(w + 6520832);           // 32*196 f32

    norm_kernel<<<4704, 256, 0, stream>>>(feats, nfeats, fH, nfH, smaxG);
    simmax_kernel<<<256, 1024, 0, stream>>>(fH, nfH, smaxG);
    finalize_kernel<<<32, 256, 0, stream>>>(smaxG, mask, patch, out);
    upsample_kernel<<<896, 256, 0, stream>>>(patch, out);
}

// Round 13
// 49.039 us; speedup vs baseline: 6.9594x; 1.2725x over previous
//
#include <hip/hip_runtime.h>
#include <hip/hip_fp16.h>

typedef __attribute__((ext_vector_type(8))) short f16x8;
typedef __attribute__((ext_vector_type(8))) _Float16 half8;
typedef __attribute__((ext_vector_type(4))) float f32x4;

__device__ __forceinline__ unsigned short f2h(float x) {
    __half h = __float2half(x);           // RNE f32 -> f16
    unsigned short u;
    __builtin_memcpy(&u, &h, 2);
    return u;
}

// async global->LDS, 16B per lane. LDS dest = wave-uniform base + lane*16.
__device__ __forceinline__ void gll16(const void* g, void* l) {
    __builtin_amdgcn_global_load_lds(
        (const __attribute__((address_space(1))) unsigned*)g,
        (__attribute__((address_space(3))) unsigned*)l, 16, 0, 0);
}

// ---------------- kernel 1: L2-normalize rows, f32 -> f16 (196-row panels) ----
__global__ __launch_bounds__(256) void norm_kernel(
    const float* __restrict__ feats, const float* __restrict__ nfeats,
    unsigned short* __restrict__ fH, unsigned short* __restrict__ nfH)
{
    int row  = blockIdx.x * 4 + (threadIdx.x >> 6);    // one wave per row, rows 0..18815
    int lane = threadIdx.x & 63;
    const float* src;
    unsigned short* dst;
    if (row < 6272) { src = feats  + (size_t)row * 128; dst = fH  + (size_t)row * 128; }
    else { int r2 = row - 6272; src = nfeats + (size_t)r2 * 128; dst = nfH + (size_t)r2 * 128; }

    float2 v = *(const float2*)(src + lane * 2);
    float ss = v.x * v.x + v.y * v.y;
    #pragma unroll
    for (int m = 1; m < 64; m <<= 1) ss += __shfl_xor(ss, m, 64);
    float rn = rsqrtf(ss);
    ushort2 o; o.x = f2h(v.x * rn); o.y = f2h(v.y * rn);
    *(ushort2*)(dst + lane * 2) = o;
}

// ---------------- kernel 2: register-resident P-operand, q streamed from LDS ----
// Stage a 196x128 f16 panel (3136 16B chunks), source-side swizzled:
// LDS slot (row, cc) holds global chunk (row, cc ^ (row&7)).  512 threads.
__device__ __forceinline__ void stage196(const f16x8* __restrict__ g, f16x8* l,
                                         int tid, int wave) {
    #pragma unroll
    for (int i = 0; i < 6; ++i) {
        int slot = i * 512 + tid;
        int row = slot >> 4, cc = slot & 15;
        gll16(g + row * 16 + (cc ^ (row & 7)), l + i * 512 + wave * 64);
    }
    if (tid < 64) {                        // tail: slots 3072..3135 (rows 192..195)
        int slot = 3072 + tid;
        int row = slot >> 4, cc = slot & 15;
        gll16(g + row * 16 + (cc ^ (row & 7)), l + 3072);
    }
}

__global__ __launch_bounds__(512, 2) void simmax_kernel(
    const unsigned short* __restrict__ fH, const unsigned short* __restrict__ nfH,
    const float* __restrict__ mask, float* __restrict__ sp, float* __restrict__ scores)
{
    __shared__ f16x8 lds[3 * 3136];       // F | B0 | B1 = 150,528 B
    __shared__ unsigned smaxL[8 * 208];   // per-(bi, p) running max of sim+3
    __shared__ unsigned scoresL[8];
    f16x8* Fl = lds;
    f16x8* B0 = lds + 3136;
    f16x8* B1 = lds + 6272;

    int a = blockIdx.x & 31, bg = blockIdx.x >> 5;   // 256 blocks = 1/CU
    int b0 = bg * 8;
    int tid = threadIdx.x, wave = tid >> 6, lane = tid & 63;
    int l15 = lane & 15, lg = lane >> 4;             // fragment row / k-group
    int pg = wave & 1, qs = wave >> 1;               // p-group (2), q-subset (4)
    int p0 = pg ? 68 : 0;                            // p-tiles p0+16*pt, pt=0..7
    const int qstart[4] = {0, 4, 7, 10};
    const int qend[4]   = {4, 7, 10, 13};

    stage196((const f16x8*)(fH  + (size_t)a  * 196 * 128), Fl, tid, wave);
    stage196((const f16x8*)(nfH + (size_t)b0 * 196 * 128), B0, tid, wave);
    for (int i = tid; i < 8 * 208; i += 512) smaxL[i] = 0u;
    if (tid < 8) scoresL[tid] = 0u;
    __syncthreads();                      // panels staged, accumulators zeroed

    // P fragments: 8 p-tiles x 4 ks, register-resident for the whole kernel.
    // frag: lane holds row (p0+pt*16+l15), k = ks*32 + lg*8 + j  (16B chunk)
    half8 pb[8][4];
    #pragma unroll
    for (int pt = 0; pt < 8; ++pt) {
        int row = p0 + pt * 16 + l15;
        #pragma unroll
        for (int ks = 0; ks < 4; ++ks) {
            pb[pt][ks] = *(const half8*)(Fl + ((row << 4) | ((ks * 4 + lg) ^ (row & 7))));
            asm volatile("" : "+v"(pb[pt][ks]));     // pin: no remat/sink
        }
    }

    for (int bi = 0; bi < 8; ++bi) {
        f16x8* Bcur = (bi & 1) ? B1 : B0;
        f16x8* Bnxt = (bi & 1) ? B0 : B1;
        if (bi < 7)                       // async; lands during this bi's compute
            stage196((const f16x8*)(nfH + (size_t)(b0 + bi + 1) * 196 * 128), Bnxt, tid, wave);

        float rmax[8];
        #pragma unroll
        for (int pt = 0; pt < 8; ++pt) rmax[pt] = -3.0f;

        for (int qi = qstart[qs]; qi < qend[qs]; ++qi) {
            int qbase = (qi < 12) ? qi * 16 : 180;   // tile 12 @180: rows all valid
            f32x4 acc[8];
            #pragma unroll
            for (int pt = 0; pt < 8; ++pt) acc[pt] = (f32x4){0.f, 0.f, 0.f, 0.f};
            #pragma unroll
            for (int ks = 0; ks < 4; ++ks) {
                int row = qbase + l15;
                half8 qa = *(const half8*)(Bcur + ((row << 4) | ((ks * 4 + lg) ^ (row & 7))));
                #pragma unroll
                for (int pt = 0; pt < 8; ++pt)
                    acc[pt] = __builtin_amdgcn_mfma_f32_16x16x32_f16(qa, pb[pt][ks], acc[pt], 0, 0, 0);
            }
            // C/D: col = lane&15 = p, row = q = 4*lg + reg. Fold 4 q's per lane.
            #pragma unroll
            for (int pt = 0; pt < 8; ++pt)
                rmax[pt] = fmaxf(rmax[pt],
                           fmaxf(fmaxf(acc[pt][0], acc[pt][1]),
                                 fmaxf(acc[pt][2], acc[pt][3])));
        }
        // merge the 4 lane-groups (q rows) via 4-way same-address LDS atomic
        #pragma unroll
        for (int pt = 0; pt < 8; ++pt)
            atomicMax(&smaxL[bi * 208 + p0 + pt * 16 + l15],
                      __float_as_uint(rmax[pt] + 3.0f));   // sim+3 > 0

        __syncthreads();                  // Bcur free for re-stage; Bnxt drained
    }

    // epilogue: one thread per p (waves 0-3), all 8 bi at once
    if (wave < 4) {
        int p = tid;                      // 0..255; valid p < 196
        float mk = (p < 196) ? mask[a * 196 + p] : 0.0f;
        float d8[8];
        #pragma unroll
        for (int bi = 0; bi < 8; ++bi) {
            float d = 0.0f;
            if (p < 196) {
                float sim = __uint_as_float(smaxL[bi * 208 + p]) - 3.0f;
                d = 0.5f * sqrtf(fmaxf(2.0f - 2.0f * sim, 0.0f)) * mk;
            }
            d8[bi] = d;
            float m = d;                  // per-b max over this wave's 64 p's
            #pragma unroll
            for (int s = 1; s < 64; s <<= 1) m = fmaxf(m, __shfl_xor(m, s, 64));
            if (lane == 0) atomicMax(&scoresL[bi], __float_as_uint(m));
        }
        if (p < 196) {
            float* dst = sp + ((size_t)a * 196 + p) * 64 + b0;
            *(f32x4*)(dst)     = (f32x4){d8[0], d8[1], d8[2], d8[3]};
            *(f32x4*)(dst + 4) = (f32x4){d8[4], d8[5], d8[6], d8[7]};
        }
    }
    __syncthreads();
    if (tid < 8)                          // block exclusively owns (a, b0+tid)
        scores[a * 64 + b0 + tid] = __uint_as_float(scoresL[tid]);
}

// ---------------- kernel 3: patch mean over b + scores mean ----
__global__ __launch_bounds__(256) void patchmean_kernel(
    const float* __restrict__ sp, const float* __restrict__ scores,
    float* __restrict__ patch, float* __restrict__ out)
{
    int a = blockIdx.x, tid = threadIdx.x;
    if (tid < 196) {
        const f32x4* v = (const f32x4*)(sp + ((size_t)a * 196 + tid) * 64);
        float s = 0.0f;
        #pragma unroll
        for (int j = 0; j < 16; ++j) { f32x4 x = v[j]; s += x[0] + x[1] + x[2] + x[3]; }
        patch[a * 196 + tid] = s * (1.0f / 64.0f);
    }
    if (tid >= 192 && tid < 256) {         // wave 3: scores mean
        int l = tid - 192;
        float s = scores[a * 64 + l];
        #pragma unroll
        for (int m = 1; m < 64; m <<= 1) s += __shfl_xor(s, m, 64);
        if (l == 0) out[a] = s * (1.0f / 64.0f);
    }
}

// ---------------- kernel 4: bilinear 14x14 -> 224x224, 8-row bands ----
__global__ __launch_bounds__(256) void upsample_kernel(
    const float* __restrict__ patch, float* __restrict__ out)
{
    int bid = blockIdx.x;
    int a = bid / 28, band = bid % 28;
    __shared__ float pt[196];
    if (threadIdx.x < 196) pt[threadIdx.x] = patch[a * 196 + threadIdx.x];
    __syncthreads();

    float* op = out + 32 + (size_t)a * 50176 + band * 8 * 224;
    for (int t = threadIdx.x; t < 8 * 224; t += 256) {
        int h = band * 8 + (t / 224), w = t % 224;
        float sh = fmaxf((h + 0.5f) * 0.0625f - 0.5f, 0.0f);   // 14/224 = 1/16
        float sw = fmaxf((w + 0.5f) * 0.0625f - 0.5f, 0.0f);
        int h0 = (int)sh, w0 = (int)sw;
        int h1 = min(h0 + 1, 13), w1 = min(w0 + 1, 13);
        float fh = sh - (float)h0, fw = sw - (float)w0;
        float v00 = pt[h0 * 14 + w0], v01 = pt[h0 * 14 + w1];
        float v10 = pt[h1 * 14 + w0], v11 = pt[h1 * 14 + w1];
        op[t] = (1.0f - fh) * ((1.0f - fw) * v00 + fw * v01)
              +         fh  * ((1.0f - fw) * v10 + fw * v11);
    }
}

extern "C" void kernel_launch(void* const* d_in, const int* in_sizes, int n_in,
                              void* d_out, int out_size, void* d_ws, size_t ws_size,
                              hipStream_t stream) {
    const float* feats  = (const float*)d_in[0];   // [32,196,128]
    const float* nfeats = (const float*)d_in[1];   // [64,196,128]
    const float* mask   = (const float*)d_in[2];   // [32,196]
    float* out = (float*)d_out;                    // 32 + 32*224*224

    char* w = (char*)d_ws;
    unsigned short* fH  = (unsigned short*)(w);            // 32*196*128 f16 = 1,605,632 B
    unsigned short* nfH = (unsigned short*)(w + 1605632);  // 64*196*128 f16 = 3,211,264 B
    float* sp     = (float*)(w + 4816896);                 // 32*196*64 f32  = 1,605,632 B
    float* scores = (float*)(w + 6422528);                 // 2048 f32
    float* patch  = (float*)(w + 6430720);                 // 32*196 f32

    norm_kernel<<<4704, 256, 0, stream>>>(feats, nfeats, fH, nfH);
    simmax_kernel<<<256, 512, 0, stream>>>(fH, nfH, mask, sp, scores);
    patchmean_kernel<<<32, 256, 0, stream>>>(sp, scores, patch, out);
    upsample_kernel<<<896, 256, 0, stream>>>(patch, out);
}